// Round 7
// baseline (394.365 us; speedup 1.0000x reference)
//
#include <hip/hip_runtime.h>
#include <math.h>

#define NG 4096
#define M 50
#define KTOP 30
#define H 32
#define F_IN 128
#define EPG 400          // edges per graph (M * DEG)
#define PADE 552         // EPG + M*3: CSR rows padded to multiples of 4
#define E_TOTAL (NG * EPG)
#define DLAT 97
#define LATS 100         // padded stride for lat tile (keeps 16B alignment)
#define NTHREADS 256
#define WS_C1P 0         // ws: C1w padded [16][100], rows 16B-aligned
#define XH 64            // x staged in two K-halves of 64 (halves LDS for xs)
#define W0TS 66          // w0t row stride: 8B-aligned, 2-way bank alias (free)
#define W12TS 34         // w1t/w2t row stride: 8B-aligned, 2-way alias

typedef float f32x2 __attribute__((ext_vector_type(2)));

// v_pk_fma_f32: packed dual fp32 FMA (VOP3P). The compiler never emits it
// for scalar code; operand pairs are memory-contiguous (K-packed) so no
// lane-packing moves are needed.
__device__ __forceinline__ f32x2 pk_fma(f32x2 a, f32x2 b, f32x2 c) {
    f32x2 d;
    asm("v_pk_fma_f32 %0, %1, %2, %3" : "=v"(d) : "v"(a), "v"(b), "v"(c));
    return d;
}

// fast tanh: 1 - 2/(e^{2x}+1). abs err ~1e-6; layers 1-3 only (layer 4 =
// sort key uses exact tanhf).
__device__ __forceinline__ float fast_tanh(float x) {
    x = fminf(fmaxf(x, -15.f), 15.f);
    float e = __expf(2.f * x);
    return 1.f - 2.f / (e + 1.f);
}

// ---- prep: pad C1w rows 97 -> 100 floats (16B-aligned rows, pad = 0) ----
__global__ void prep_kernel(const float* __restrict__ C1w, float* __restrict__ ws) {
    const int tid = blockIdx.x * blockDim.x + threadIdx.x;
    if (tid < 1600) {
        int c = tid / 100, d = tid - c * 100;
        ws[WS_C1P + tid] = (d < DLAT) ? C1w[c * DLAT + d] : 0.f;
    }
}

// -------- GCN matmul core (all-LDS operands, pk_fma, unroll-2) ------------
// R7: W transposed in LDS (wt[j][k]) so even/odd-K pairs are contiguous ->
// v_pk_fma_f32 halves the FMA stream with zero packing moves. Per k4:
// 2 b64 (w) + 14 b64 (x, broadcast) + 14 pk_fma = 30 issue vs 39 scalar.
// acc2[r] = {even-K sum, odd-K sum}; horizontal add in the epilogue.
// wtj = &wt[j][0] (caller-resolved). UNROLL 2 EXACTLY (r10 spill lesson).
template <int KIN>
__device__ __forceinline__ void gcn_matmul_acc(const float* hin, int istride,
                                               const float* wtj,
                                               const int* rows, f32x2* acc2) {
#pragma unroll 2
    for (int k4 = 0; k4 < KIN / 4; k4++) {
        const f32x2 wA = *(const f32x2*)(wtj + 4 * k4);
        const f32x2 wB = *(const f32x2*)(wtj + 4 * k4 + 2);
#pragma unroll
        for (int r = 0; r < 7; r++) {
            const f32x2* xp = (const f32x2*)(hin + rows[r] * istride + 4 * k4);
            acc2[r] = pk_fma(xp[0], wA, acc2[r]);
            acc2[r] = pk_fma(xp[1], wB, acc2[r]);
        }
    }
}

// full matmul for layers 2/3: tn[i][j] = dinv[i] * sum_k hin[i*istride+k]*Wt[j][k].
// PRE-SCALED by dinv[row]. thread (iset=tid>>5, j=tid&31) owns rows
// {iset, iset+8, ..., iset+48}; row 49 recomputed by 6 threads (clamp).
template <int KIN>
__device__ __forceinline__ void gcn_matmul(const float* hin, int istride,
                                           const float* wtj,
                                           float (*tb)[H], const float* dinv, int tid) {
    const int j = tid & 31, iset = tid >> 5;
    f32x2 acc[7];
    int rows[7];
#pragma unroll
    for (int r = 0; r < 7; r++) {
        acc[r] = (f32x2){0.f, 0.f};
        int i = iset + r * 8;
        rows[r] = (i >= M) ? (M - 1) : i;
    }
    __builtin_amdgcn_s_setprio(1);
    gcn_matmul_acc<KIN>(hin, istride, wtj, rows, acc);
    __builtin_amdgcn_s_setprio(0);
#pragma unroll
    for (int r = 0; r < 7; r++) {
        int i = iset + r * 8;
        if (i < M) tb[i][j] = (acc[r].x + acc[r].y) * dinv[i];
    }
}

// aggregation + bias + tanh on PRE-SCALED tn: acc = tn[i] + sum_s tn[s];
// out = tanh(dinv[i]*acc + b). Padded CSR rows are multiples of 4; pad slots
// hold sentinel src=M (tn[M][*]==0), so the body is branch-free.
__device__ __forceinline__ void gcn_agg(const float (*tbuf)[H], const float* __restrict__ b,
                                        float (*lat)[LATS], int col0,
                                        const float* dinv, const unsigned short* csr_off,
                                        const unsigned char* csr_src, int tid) {
    const int j = tid & 31, iset = tid >> 5;
    for (int i = iset; i < M; i += 8) {
        float acc = tbuf[i][j];                      // self (prescaled)
        int e0 = csr_off[i], e1 = csr_off[i + 1];
        for (int e = e0; e < e1; e += 4) {
            unsigned sp = *(const unsigned*)(csr_src + e);
            acc += tbuf[sp & 255][j];
            acc += tbuf[(sp >> 8) & 255][j];
            acc += tbuf[(sp >> 16) & 255][j];
            acc += tbuf[sp >> 24][j];
        }
        lat[i][col0 + j] = fast_tanh(acc * dinv[i] + b[j]);
    }
}

struct Post {                                      // 3392 B tail (phase union)
    float pbuf[16][15];
    union {
        struct { float z1[16][KTOP]; unsigned char ord[52]; } a;
        struct { float z2[352]; float red[256]; } b;
    } u;
};

// (256,4): spill-free point (64 VGPR). R3 proved arg2 is NOT an occupancy
// ceiling; keep the known-good schedule. TRIPWIRE this round: pk_fma acc2
// doubles accumulator regs -- a spill shows as WRITE_SIZE ballooning.
__global__ __launch_bounds__(NTHREADS, 4)
void dgcnn_kernel(const float* __restrict__ x, const int* __restrict__ eidx,
                  const float* __restrict__ ws,
                  const float* __restrict__ W0, const float* __restrict__ b0,
                  const float* __restrict__ W1, const float* __restrict__ b1,
                  const float* __restrict__ W2, const float* __restrict__ b2,
                  const float* __restrict__ W3, const float* __restrict__ b3,
                  const float* __restrict__ C1b,
                  const float* __restrict__ C2w, const float* __restrict__ C2b,
                  const float* __restrict__ L1w, const float* __restrict__ L1b,
                  const float* __restrict__ L2w, const float* __restrict__ L2b,
                  float* __restrict__ out) {
    // LDS plan (R7): transposed weights.
    //   Big: p1{xs 12800 + w0t[32][66] 8448} = 21248 vs lat 20000 -> 21248
    //   TP 6528, w12u max(w1t+w2t 8704, c2w 10240) = 10240, csr_src 552,
    //   csr_off 104, degi 200, dinv 200 -> 39072 B; 4 x 39.1 KB = 156 KB.
    __shared__ __align__(16) union Big {
        struct { float xs[M][XH]; float w0t[H][W0TS]; } p1;  // 21248 B
        float lat[M][LATS];                                  // 20000 B
    } big;
    __shared__ __align__(16) union TP {
        float tbuf[M + 1][H];              //  6528 B, dies after layer-4 agg
        Post post;                         //  3392 B, born at sort
    } tp;
    __shared__ __align__(16) union W12U {
        float w[2][H][W12TS];              //  8704 B: W1t, W2t (die layer-3 mm)
        float c2w[32 * 16 * 5];            // 10240 B: conv2 weights (born agg-3)
    } w12u;
    __shared__ unsigned char csr_src[PADE];        //   552 B
    __shared__ unsigned short csr_off[M + 2];      //   104 B
    __shared__ int   degi[M];                      //   200 B (becomes cursor)
    __shared__ float dinv[M];                      //   200 B

    const int g = blockIdx.x;
    const int tid = threadIdx.x;
    const int nbase = g * M;
    const int ebase = g * EPG;

    // ---- stage x half 0 + W0t half 0 + W1t/W2t -> LDS ----
    // W transpose staging: read float4 along j (coalesced), write 4 LDS b32
    // at wt[j][k] (2-way bank alias across the wave = free).
    {
        const float4* xg4 = (const float4*)(x + (size_t)nbase * F_IN);
        float4* xs4 = (float4*)big.p1.xs;
        for (int idx = tid; idx < M * XH / 4; idx += NTHREADS) {
            int i = idx >> 4, q = idx & 15;          // 16 float4 per xs row
            xs4[idx] = xg4[i * 32 + q];              // 32 float4 per x row
        }
        const float4* w0g = (const float4*)W0;       // rows k = 0..63
        for (int idx = tid; idx < 512; idx += NTHREADS) {
            int k = idx >> 3, q4 = (idx & 7) * 4;
            float4 v = w0g[idx];
            big.p1.w0t[q4 + 0][k] = v.x; big.p1.w0t[q4 + 1][k] = v.y;
            big.p1.w0t[q4 + 2][k] = v.z; big.p1.w0t[q4 + 3][k] = v.w;
        }
        for (int idx = tid; idx < 512; idx += NTHREADS) {
            int m = idx >> 8, r = idx & 255;
            int k = r >> 3, q4 = (r & 7) * 4;
            float4 v = ((const float4*)(m ? W2 : W1))[r];
            w12u.w[m][q4 + 0][k] = v.x; w12u.w[m][q4 + 1][k] = v.y;
            w12u.w[m][q4 + 2][k] = v.z; w12u.w[m][q4 + 3][k] = v.w;
        }
    }
    // ---- init: degrees + sentinel-fill padded CSR src (0x32 = row M) ----
    if (tid < M) degi[tid] = 1;
    for (int idx = tid; idx < PADE / 4; idx += NTHREADS)
        ((unsigned*)csr_src)[idx] = 0x32323232u;
    __syncthreads();
    for (int e = tid; e < EPG; e += NTHREADS) {
        int d = eidx[E_TOTAL + ebase + e] - nbase;
        atomicAdd(&degi[d], 1);
    }
    __syncthreads();
    // ---- dinv + padded-CSR offsets (wave-0 shuffle scan); cursor=degi ----
    if (tid < M) dinv[tid] = rsqrtf((float)degi[tid]);
    if (tid < 64) {
        int cnt  = (tid < M) ? (degi[tid] - 1) : 0;
        int cntp = (cnt + 3) & ~3;
        int incl = cntp;
#pragma unroll
        for (int off = 1; off < 64; off <<= 1) {
            int nv = __shfl_up(incl, off);
            if (tid >= off) incl += nv;
        }
        if (tid < M) {
            csr_off[tid] = (unsigned short)(incl - cntp);
            degi[tid] = incl - cntp;
        }
        if (tid == M - 1) csr_off[M] = (unsigned short)incl;
    }
    __syncthreads();
    // ---- CSR fill + layer-1 matmul half 0 (independent; one barrier) ----
    const int j1 = tid & 31, iset1 = tid >> 5;
    const float* w0tj = &big.p1.w0t[j1][0];
    f32x2 acc1[7];
    int rows1[7];
#pragma unroll
    for (int r = 0; r < 7; r++) {
        acc1[r] = (f32x2){0.f, 0.f};
        int i = iset1 + r * 8;
        rows1[r] = (i >= M) ? (M - 1) : i;
    }
    for (int e = tid; e < EPG; e += NTHREADS) {
        int s = eidx[ebase + e] - nbase;
        int d = eidx[E_TOTAL + ebase + e] - nbase;
        int pos = atomicAdd(&degi[d], 1);
        csr_src[pos] = (unsigned char)s;
    }
    __builtin_amdgcn_s_setprio(1);
    gcn_matmul_acc<XH>(&big.p1.xs[0][0], XH, w0tj, rows1, acc1);
    __builtin_amdgcn_s_setprio(0);
    __syncthreads();                     // all reads of xs/w0t half 0 done
    // ---- stage x half 1 + W0t half 1 (rows 64..127); acc1 in regs ----
    {
        const float4* xg4 = (const float4*)(x + (size_t)nbase * F_IN);
        float4* xs4 = (float4*)big.p1.xs;
        for (int idx = tid; idx < M * XH / 4; idx += NTHREADS) {
            int i = idx >> 4, q = idx & 15;
            xs4[idx] = xg4[i * 32 + 16 + q];
        }
        const float4* w0g = (const float4*)(W0 + XH * H);
        for (int idx = tid; idx < 512; idx += NTHREADS) {
            int k = idx >> 3, q4 = (idx & 7) * 4;
            float4 v = w0g[idx];
            big.p1.w0t[q4 + 0][k] = v.x; big.p1.w0t[q4 + 1][k] = v.y;
            big.p1.w0t[q4 + 2][k] = v.z; big.p1.w0t[q4 + 3][k] = v.w;
        }
    }
    __syncthreads();
    __builtin_amdgcn_s_setprio(1);
    gcn_matmul_acc<XH>(&big.p1.xs[0][0], XH, w0tj, rows1, acc1);
    __builtin_amdgcn_s_setprio(0);
#pragma unroll
    for (int r = 0; r < 7; r++) {
        int i = iset1 + r * 8;
        if (i < M) tp.tbuf[i][j1] = (acc1[r].x + acc1[r].y) * dinv[i];
    }
    if (tid < H) tp.tbuf[M][tid] = 0.f;  // sentinel row for CSR pad slots
    __syncthreads();                     // xs/w0t dead from here; lat live

    // ---- layer 1 agg -> lat[:,0:32]; also zero lat pad cols 97..99 ----
    gcn_agg(tp.tbuf, b0, big.lat, 0, dinv, csr_off, csr_src, tid);
    for (int idx = tid; idx < 3 * M; idx += NTHREADS)
        big.lat[idx / 3][DLAT + idx % 3] = 0.f;     // conv1 reads 100 cols
    __syncthreads();
    // ---- layer 2 (W1t from LDS) ----
    gcn_matmul<H>(&big.lat[0][0], LATS, &w12u.w[0][tid & 31][0], tp.tbuf, dinv, tid);
    __syncthreads();
    gcn_agg(tp.tbuf, b1, big.lat, 32, dinv, csr_off, csr_src, tid);
    __syncthreads();
    // ---- layer 3 (W2t from LDS) ----
    gcn_matmul<H>(&big.lat[0][32], LATS, &w12u.w[1][tid & 31][0], tp.tbuf, dinv, tid);
    __syncthreads();                     // w12u.w dead after this barrier
    // ---- layer 3 agg + C2w -> LDS stage (independent; same phase) ----
    gcn_agg(tp.tbuf, b2, big.lat, 64, dinv, csr_off, csr_src, tid);
    {
        float4* cf = (float4*)w12u.c2w;              // 640 float4 = 10240 B
        const float4* cg = (const float4*)C2w;
        for (int idx = tid; idx < 640; idx += NTHREADS)
            cf[idx] = cg[idx];
    }
    __syncthreads();
    // ---- layer 4 (H -> 1): exact tanhf (sort key) ----
    if (tid < M) {
        float acc = 0.f;
        for (int k = 0; k < H; k++) acc += big.lat[tid][64 + k] * W3[k];
        tp.tbuf[tid][0] = acc * dinv[tid];
    }
    __syncthreads();
    if (tid < M) {
        float acc = tp.tbuf[tid][0];
        int e0 = csr_off[tid], e1 = csr_off[tid + 1];
        for (int e = e0; e < e1; e += 4) {
            unsigned sp = *(const unsigned*)(csr_src + e);
            acc += tp.tbuf[sp & 255][0] + tp.tbuf[(sp >> 8) & 255][0]
                 + tp.tbuf[(sp >> 16) & 255][0] + tp.tbuf[sp >> 24][0];
        }
        big.lat[tid][96] = tanhf(acc * dinv[tid] + b3[0]);
    }
    __syncthreads();                     // tbuf dead from here; post live

    // ---- sort-pool: stable descending rank over lat[:,96] ----
    if (tid < M) {
        float v = big.lat[tid][96];
        int r = 0;
        for (int jj = 0; jj < M; jj++) {
            float vj = big.lat[jj][96];
            r += (vj > v) || (vj == v && jj < tid);
        }
        tp.post.u.a.ord[r] = (unsigned char)tid;
    }
    __syncthreads();

    // ---- Conv1d(1,16,97,stride 97) + ReLU, pk_fma over d pairs ----
    // t=idx>>4: 16 lanes share a row -> LDS b64 broadcast; C1P rows (ws)
    // are 100 floats (8B-aligned), pad cols = 0. 2 packed accs = 2-way ILP.
    for (int idx = tid; idx < 16 * KTOP; idx += NTHREADS) {
        int t = idx >> 4, c = idx & 15;
        const f32x2* row2 = (const f32x2*)big.lat[tp.post.u.a.ord[t]];
        const f32x2* cw2  = (const f32x2*)(ws + WS_C1P + c * LATS);
        f32x2 a01 = (f32x2){0.f, 0.f}, a23 = (f32x2){0.f, 0.f};
#pragma unroll 5
        for (int q = 0; q < LATS / 4; q++) {
            a01 = pk_fma(row2[2 * q],     cw2[2 * q],     a01);
            a23 = pk_fma(row2[2 * q + 1], cw2[2 * q + 1], a23);
        }
        float acc = (a01.x + a01.y) + (a23.x + a23.y);
        tp.post.u.a.z1[c][t] = fmaxf(acc + C1b[c], 0.f);
    }
    __syncthreads();

    // ---- MaxPool1d(2,2) -> pbuf (outside inner union) ----
    for (int idx = tid; idx < 16 * 15; idx += NTHREADS) {
        int c = idx / 15, t = idx - c * 15;
        tp.post.pbuf[c][t] = fmaxf(tp.post.u.a.z1[c][2 * t],
                                   tp.post.u.a.z1[c][2 * t + 1]);
    }
    __syncthreads();

    // ---- Conv1d(16,32,5) + ReLU, flatten f = o*11 + t (C2w from LDS) ----
    // 2 independent accs (even/odd i) halve the serial FMA chain.
    for (int idx = tid; idx < 352; idx += NTHREADS) {
        int o = idx / 11, t = idx - o * 11;
        float a0 = C2b[o], a1 = 0.f;
        for (int i = 0; i < 16; i += 2) {
#pragma unroll
            for (int k = 0; k < 5; k++) {
                a0 += tp.post.pbuf[i][t + k]     * w12u.c2w[(o * 16 + i) * 5 + k];
                a1 += tp.post.pbuf[i + 1][t + k] * w12u.c2w[(o * 16 + i + 1) * 5 + k];
            }
        }
        tp.post.u.b.z2[idx] = fmaxf(a0 + a1, 0.f);
    }
    __syncthreads();

    // ---- Dense 352 -> 128 + ReLU (split over 2 halves; coalesced L1w) ----
    // 4 independent accumulators: breaks the single FMA dep chain and lets
    // more coalesced L1w loads pipeline within the 64-VGPR budget.
    {
        int jj = tid & 127, half = tid >> 7;
        int f0 = half * 176;
        const float* Lp = L1w + (size_t)f0 * 128 + jj;
        const float* zp = tp.post.u.b.z2 + f0;
        float a0 = 0.f, a1 = 0.f, a2 = 0.f, a3 = 0.f;
#pragma unroll 2
        for (int f = 0; f < 176; f += 4) {
            a0 += zp[f]     * Lp[(f)     * 128];
            a1 += zp[f + 1] * Lp[(f + 1) * 128];
            a2 += zp[f + 2] * Lp[(f + 2) * 128];
            a3 += zp[f + 3] * Lp[(f + 3) * 128];
        }
        float acc = (a0 + a1) + (a2 + a3) + ((half == 0) ? L1b[jj] : 0.f);
        tp.post.u.b.red[tid] = acc;
    }
    __syncthreads();
    // ---- fuse ReLU + Dense 128 -> 1 ----
    if (tid < 128)
        tp.post.u.b.red[tid] =
            fmaxf(tp.post.u.b.red[tid] + tp.post.u.b.red[tid + 128], 0.f)
            * L2w[tid];
    __syncthreads();
    if (tid < 64) {
        float v = tp.post.u.b.red[tid] + tp.post.u.b.red[tid + 64];
#pragma unroll
        for (int off = 32; off >= 1; off >>= 1)
            v += __shfl_down(v, off);
        if (tid == 0) out[g] = v + L2b[0];
    }
}

extern "C" void kernel_launch(void* const* d_in, const int* in_sizes, int n_in,
                              void* d_out, int out_size, void* d_ws, size_t ws_size,
                              hipStream_t stream) {
    const float* x    = (const float*)d_in[0];
    const int*   eidx = (const int*)d_in[1];
    // d_in[2] (batch) unused: graphs are contiguous equal-size blocks
    float* ws = (float*)d_ws;
    prep_kernel<<<7, 256, 0, stream>>>((const float*)d_in[11], ws);
    dgcnn_kernel<<<NG, NTHREADS, 0, stream>>>(
        x, eidx, ws,
        (const float*)d_in[3],  (const float*)d_in[4],
        (const float*)d_in[5],  (const float*)d_in[6],
        (const float*)d_in[7],  (const float*)d_in[8],
        (const float*)d_in[9],  (const float*)d_in[10],
        (const float*)d_in[12],
        (const float*)d_in[13], (const float*)d_in[14],
        (const float*)d_in[15], (const float*)d_in[16],
        (const float*)d_in[17], (const float*)d_in[18],
        (float*)d_out);
}